// Round 11
// baseline (442.301 us; speedup 1.0000x reference)
//
#include <hip/hip_runtime.h>
#include <stdint.h>

#define DEVFN __device__ __forceinline__

typedef __attribute__((ext_vector_type(8))) short s16x8;
typedef __attribute__((ext_vector_type(4))) float f32x4;

DEVFN float bf2f(uint16_t u) {
  union { uint32_t i; float f; } v; v.i = ((uint32_t)u) << 16; return v.f;
}
DEVFN uint16_t f2bf(float f) {
  union { float f; uint32_t i; } v; v.f = f;
  uint32_t u = v.i;
  return (uint16_t)((u + 0x7FFFu + ((u >> 16) & 1u)) >> 16);
}

DEVFN void gload_lds16(const void* g, void* l) {
  __builtin_amdgcn_global_load_lds(
      (const __attribute__((address_space(1))) uint32_t*)g,
      (__attribute__((address_space(3))) uint32_t*)l, 16, 0, 0);
}

// Grid barrier: monotonic counter (zeroed by prep each iteration).
// Writer side: __threadfence (device-scope release: wb L2) before arrive;
// reader side: __threadfence after (acquire: inv stale caches) -> safe
// cross-XCD producer/consumer. Co-residency by construction: 64KB LDS
// caps occupancy at 2 blocks/CU, launch_bounds(256,2) caps VGPR for it,
// grid = 512 = 2 x 256 CUs -> ALL blocks dispatch immediately (regular
// launch; r10 showed hipLaunchCooperativeKernel dies under graph capture).
DEVFN void gbar(unsigned* cnt, unsigned tgt)
{
  __syncthreads();
  if (threadIdx.x == 0) {
    __threadfence();
    __hip_atomic_fetch_add(cnt, 1u, __ATOMIC_ACQ_REL, __HIP_MEMORY_SCOPE_AGENT);
    while (__hip_atomic_load(cnt, __ATOMIC_ACQUIRE, __HIP_MEMORY_SCOPE_AGENT) < tgt)
      __builtin_amdgcn_s_sleep(2);
  }
  __syncthreads();
  __threadfence();
}

// ---------------------------------------------------------------------------
// Fused prep: blocks 0..2047  : x -> Xh (hi) + XR = BN(AvgPool4) hi ONLY
//             blocks 2048..5119: Wk/Wv -> Wkvh (hi), Wp -> Wph (hi)
// Also zeroes the mono-kernel grid-barrier counter (block 0 thread 0).
// ---------------------------------------------------------------------------
__global__ __launch_bounds__(256)
void prep_kernel(const float* __restrict__ x,
                 const float* __restrict__ bn_g, const float* __restrict__ bn_b,
                 const float* __restrict__ bn_m, const float* __restrict__ bn_v,
                 const float* __restrict__ Wk, const float* __restrict__ Wv,
                 const float* __restrict__ Wp,
                 uint16_t* __restrict__ Xh,
                 uint16_t* __restrict__ XRh,
                 uint16_t* __restrict__ Wkvh,
                 uint16_t* __restrict__ Wph,
                 unsigned* __restrict__ cnt)
{
  const int t = threadIdx.x;
  const int bid = blockIdx.x;
  if (bid == 0 && t == 0) *cnt = 0;          // reset mono barrier counter
  if (bid < 2048) {
    const int prow = bid;                    // pooled row: b*512 + mm
    const int c0 = t * 4;
    const size_t xbase = (size_t)prow * 4096 + c0;   // x row prow*4
    float s[4] = {0.f, 0.f, 0.f, 0.f};
#pragma unroll
    for (int r = 0; r < 4; ++r) {
      const float4 w = *(const float4*)(x + xbase + (size_t)r * 1024);
      const float vv[4] = { w.x, w.y, w.z, w.w };
      uint64_t wh = 0;
#pragma unroll
      for (int j = 0; j < 4; ++j) {
        wh |= ((uint64_t)f2bf(vv[j])) << (16 * j);
        s[j] += vv[j];
      }
      *(uint64_t*)(Xh + xbase + (size_t)r * 1024) = wh;
    }
    uint64_t wh = 0;
#pragma unroll
    for (int j = 0; j < 4; ++j) {
      const int c = c0 + j;
      const float y = (s[j] * 0.25f - bn_m[c]) / sqrtf(bn_v[c] + 1e-6f) * bn_g[c] + bn_b[c];
      wh |= ((uint64_t)f2bf(y)) << (16 * j);
    }
    *(uint64_t*)(XRh + (size_t)prow * 1024 + c0) = wh;
  } else {
    const int wb = bid - 2048;               // 0..3071
    const int which = wb >> 10;
    const int i = (wb & 1023) * 256 + t;     // float4 index
    const float* src = (which == 0) ? Wk : (which == 1) ? Wv : Wp;
    const float4 v = ((const float4*)src)[i];
    const float vv[4] = { v.x, v.y, v.z, v.w };
    uint64_t wh = 0;
#pragma unroll
    for (int j = 0; j < 4; ++j)
      wh |= ((uint64_t)f2bf(vv[j])) << (16 * j);
    if (which == 2) {
      ((uint64_t*)Wph)[i] = wh;
    } else {
      ((uint64_t*)Wkvh)[(size_t)which * (1024 * 1024 / 4) + i] = wh;
    }
  }
}

// ---------------------------------------------------------------------------
// NT GEMM phase body — byte-for-byte the r6 champion (measured 85.47):
// single LDS buffer, BK=128, 16x16x32 MFMA, register-frontload reorder.
// blockIdx/gridDim are parameters so it can run inside the mono kernel.
// ---------------------------------------------------------------------------
template<bool BATCHB, bool AMODA, int EPI, bool KSPLIT2, bool SMALLM>
DEVFN void gemm_body(char* smem,
                     const uint16_t* __restrict__ A0,
                     const uint16_t* __restrict__ B0,
                     float* __restrict__ C32, uint16_t* __restrict__ Cb0,
                     const float* __restrict__ bias,
                     int M, int N, int K, int rows_per_batch,
                     int bidx, int bidy, int nwg)
{
  constexpr int BM = SMALLM ? 64 : 128, BN = 128, BK = 128;
  constexpr int WCN = SMALLM ? 4 : 2;         // waves along N
  constexpr int WNW = BN / WCN;               // per-wave N width (32 or 64)
  constexpr int NREP = WNW / 16;              // 2 or 4
  constexpr int APASS = SMALLM ? 4 : 8;       // A staging passes (4KB each)
  constexpr int BPASS = 8;                    // B staging passes
  uint16_t* sA = (uint16_t*)smem;
  uint16_t* sB = (uint16_t*)(smem + (size_t)BM * BK * 2);

  const int t = threadIdx.x;
  const int lane = t & 63;
  const int wave = t >> 6;
  const int wr = wave / WCN, wc = wave % WCN;
  const int fq = lane >> 4, fr = lane & 15;

  // T1: XCD-chunked swizzle (nwg divisible by 8 for all our grids)
  const int cpx = nwg >> 3;
  const int orig = bidx;
  const int swz = (orig & 7) * cpx + (orig >> 3);
  const int nbx = N >> 7;
  const int bm = (swz / nbx) * BM;
  const int bn = (swz % nbx) * BN;

  const uint16_t* Ap = A0;
  const uint16_t* Bp = B0;
  if (BATCHB)
    Bp += (size_t)(bm / rows_per_batch) * (size_t)N * (size_t)K;
  if (KSPLIT2) {
    const size_t half = (size_t)bidy * M * N;
    if (EPI == 1) Cb0 += half; else C32 += half;
  }

  f32x4 acc[4][NREP];
#pragma unroll
  for (int m = 0; m < 4; ++m)
#pragma unroll
    for (int n = 0; n < NREP; ++n) acc[m][n] = (f32x4)0.0f;

  auto STAGE = [&](int kt) {
#pragma unroll
    for (int i = 0; i < APASS; ++i) {
      const int X = t * 16 + i * 4096;          // linear LDS byte dest
      const int r = X >> 8;                     // row (256B per row)
      const int g = ((X >> 4) & 15) ^ (r & 7);  // pre-swizzled source slot
      const int kcol = (kt << 7) + g * 8;
      const int arow = AMODA ? ((bm + r) & 1023) : (bm + r);
      gload_lds16(Ap + (size_t)arow * K + kcol, (char*)sA + X);
    }
#pragma unroll
    for (int i = 0; i < BPASS; ++i) {
      const int X = t * 16 + i * 4096;
      const int r = X >> 8;
      const int g = ((X >> 4) & 15) ^ (r & 7);
      const int kcol = (kt << 7) + g * 8;
      gload_lds16(Bp + (size_t)(bn + r) * K + kcol, (char*)sB + X);
    }
  };

  const int nkt = K >> (KSPLIT2 ? 8 : 7);
  const int kt0 = KSPLIT2 ? (bidy * nkt) : 0;
  const int ktend = kt0 + nkt;

  STAGE(kt0);                                  // prologue prefetch
  for (int kt = kt0; kt < ktend; ++kt) {
    // drains this wave's staging loads (vmcnt 0) + barrier: tile kt ready
    __syncthreads();

    // front-load the whole tile's fragments into registers
    s16x8 av[4][4], bv[4][NREP];               // [ks][.]
#pragma unroll
    for (int ks = 0; ks < 4; ++ks) {
#pragma unroll
      for (int m = 0; m < 4; ++m) {
        const int ra = wr * 64 + m * 16 + fr;
        const int offA = ra * 256 + ((((ks << 2) + fq) ^ (ra & 7)) << 4);
        av[ks][m] = *(const s16x8*)((const char*)sA + offA);
      }
#pragma unroll
      for (int n = 0; n < NREP; ++n) {
        const int rb = wc * WNW + n * 16 + fr;
        const int offB = rb * 256 + ((((ks << 2) + fq) ^ (rb & 7)) << 4);
        bv[ks][n] = *(const s16x8*)((const char*)sB + offB);
      }
    }

    // lgkm drained by syncthreads; LDS buffer dead -> overwrite it early
    __syncthreads();
    if (kt + 1 < ktend) STAGE(kt + 1);

    // MFMA phase on registers (latency cover for kt+1's loads)
#pragma unroll
    for (int ks = 0; ks < 4; ++ks)
#pragma unroll
      for (int m = 0; m < 4; ++m)
#pragma unroll
        for (int n = 0; n < NREP; ++n)
          acc[m][n] = __builtin_amdgcn_mfma_f32_16x16x32_bf16(
              av[ks][m], bv[ks][n], acc[m][n], 0, 0, 0);
  }

  // epilogue: C/D layout col = lane&15, row = (lane>>4)*4 + reg (m89/m91)
#pragma unroll
  for (int m = 0; m < 4; ++m) {
#pragma unroll
    for (int n = 0; n < NREP; ++n) {
#pragma unroll
      for (int j = 0; j < 4; ++j) {
        const int row = bm + wr * 64 + m * 16 + fq * 4 + j;
        const int col = bn + wc * WNW + n * 16 + fr;
        const size_t idx = (size_t)row * N + col;
        float v = acc[m][n][j];
        if constexpr (EPI == 0) {
          C32[idx] = v;
        } else if constexpr (EPI == 1) {
          Cb0[idx] = f2bf(v);
        } else {
          C32[idx] = v + bias[col];
        }
      }
    }
  }
}

// ---------------------------------------------------------------------------
// kv1 phase body (r6 kv1_kernel): partial[wid][f][e] = sum_64rows K*V.
// KVcat bf16 in TWO split-K halves; summed fp32 on stage. wid = bh*8+ch.
// Leading __syncthreads so back-to-back calls can reuse the LDS arena.
// ---------------------------------------------------------------------------
DEVFN void kv1_body(char* smem, const uint16_t* __restrict__ KVcat,
                    float* __restrict__ part, int wid)
{
  float (*sK)[32] = (float(*)[32])smem;
  float (*sV)[32] = (float(*)[32])(smem + 8192);
  const int bh = wid >> 3, ch = wid & 7;
  const int b = bh >> 5, h = bh & 31;
  const int t = threadIdx.x;
  const int f = t >> 3, e0 = (t & 7) * 4;
  const int lr = t >> 2, q = t & 3;
  const size_t rowb = (size_t)(b * 512 + ch * 64 + lr) * 2048 + h * 32 + q * 8;
  const size_t H = (size_t)2048 * 2048;   // second split-K half offset
  const s16x8 k0 = *(const s16x8*)(KVcat + rowb);
  const s16x8 k1 = *(const s16x8*)(KVcat + H + rowb);
  const s16x8 v0 = *(const s16x8*)(KVcat + rowb + 1024);
  const s16x8 v1 = *(const s16x8*)(KVcat + H + rowb + 1024);
  __syncthreads();                         // prior users of smem done
#pragma unroll
  for (int j = 0; j < 8; ++j) {
    sK[lr][q * 8 + j] = bf2f((uint16_t)k0[j]) + bf2f((uint16_t)k1[j]);
    sV[lr][q * 8 + j] = bf2f((uint16_t)v0[j]) + bf2f((uint16_t)v1[j]);
  }
  __syncthreads();
  float a0 = 0.f, a1 = 0.f, a2 = 0.f, a3 = 0.f;
#pragma unroll 16
  for (int mm = 0; mm < 64; ++mm) {
    const float kf = sK[mm][f];
    const float4 vv = *(const float4*)&sV[mm][e0];
    a0 += kf * vv.x; a1 += kf * vv.y; a2 += kf * vv.z; a3 += kf * vv.w;
  }
  float* o = part + ((size_t)wid * 32 + f) * 32 + e0;
  o[0] = a0; o[1] = a1; o[2] = a2; o[3] = a3;
}

// ---------------------------------------------------------------------------
// t phase body (r6 t_kernel): KV[b,h] = scale * sum_ch part;
// Tt[b][c][h*32+e] = sum_f KV[f][e] * Wq[h*32+f, c]  (bf16 hi out)
// ---------------------------------------------------------------------------
DEVFN void t_body(char* smem, const float* __restrict__ part,
                  const float* __restrict__ Wq, uint16_t* __restrict__ Tth,
                  int bid)
{
  float (*sKV)[32] = (float(*)[32])smem;   // [f][e]
  const int b = bid >> 7, h = (bid >> 2) & 31, cc = bid & 3;
  const int bh = b * 32 + h;
  const int t = threadIdx.x;
  {
    const int f = t >> 3, e0 = (t & 7) * 4;
    f32x4 a = (f32x4)0.0f;
#pragma unroll
    for (int ch = 0; ch < 8; ++ch)
      a += *(const f32x4*)(part + ((size_t)(bh * 8 + ch) * 32 + f) * 32 + e0);
    a *= 0.17677669529663687f;       // 1/sqrt(32)
    *(f32x4*)&sKV[f][e0] = a;
  }
  __syncthreads();
  const int c = cc * 256 + t;
  f32x4 acc[8];
#pragma unroll
  for (int i = 0; i < 8; ++i) acc[i] = (f32x4)0.0f;
  const float* wqp = Wq + (size_t)(h * 32) * 1024 + c;
#pragma unroll 8
  for (int f = 0; f < 32; ++f) {
    const float wq = wqp[(size_t)f * 1024];
#pragma unroll
    for (int i = 0; i < 8; ++i) {
      const f32x4 kv = *(const f32x4*)&sKV[f][i * 4];
      acc[i] += kv * wq;
    }
  }
  const size_t o = (((size_t)b << 10) + c) * 1024 + h * 32;
#pragma unroll
  for (int i = 0; i < 8; ++i) {
    uint64_t wh = 0;
#pragma unroll
    for (int j = 0; j < 4; ++j)
      wh |= ((uint64_t)f2bf(acc[i][j])) << (16 * j);
    *(uint64_t*)(Tth + o + i * 4) = wh;
  }
}

// ---------------------------------------------------------------------------
// Mono kernel (r11): GEMM2 + kv1 + t + GEMM5 + GEMM6 in ONE REGULAR
// dispatch (r10's cooperative launch never executed under graph capture),
// grid barriers between phases. 512 blocks x 256 threads, 64KB LDS ->
// exactly 2 blocks/CU -> all 512 blocks resident by construction.
// Phase bodies identical to the r6 champion.
// ---------------------------------------------------------------------------
struct MonoArgs {
  const uint16_t* XRh; const uint16_t* Wkvh;
  const uint16_t* Xh;  const uint16_t* Wph;
  uint16_t* KVcat; uint16_t* Tth; uint16_t* Gh; float* KVpart;
  const float* Wq; const float* bp; float* out;
  unsigned* cnt;
};

__global__ __launch_bounds__(256, 2)
void mono_kernel(MonoArgs a)
{
  __shared__ __align__(16) char smem[65536];
  const int bid = blockIdx.x;                // 0..511

  // phase 1: [K|V] GEMM, split-K x2 (r6 GEMM2; x = bid&255, y = bid>>8)
  gemm_body<false, false, 1, true, false>(
      smem, a.XRh, a.Wkvh, nullptr, a.KVcat, nullptr,
      2048, 2048, 1024, 1 << 30, bid & 255, bid >> 8, 256);
  gbar(a.cnt, 512u * 1);

  // phase 2: KV partials (1024 works -> 2 per block)
  kv1_body(smem, a.KVcat, a.KVpart, bid * 2);
  kv1_body(smem, a.KVcat, a.KVpart, bid * 2 + 1);
  gbar(a.cnt, 512u * 2);

  // phase 3: Tt = (blockdiag(KV)^T Wq)^T
  t_body(smem, a.KVpart, a.Wq, a.Tth, bid);
  gbar(a.cnt, 512u * 3);

  // phase 4: G[b] = Wph @ Tt[b]^T (SMALLM)
  gemm_body<true, true, 1, false, true>(
      smem, a.Wph, a.Tth, nullptr, a.Gh, nullptr,
      4096, 1024, 1024, 1024, bid, 0, 512);
  gbar(a.cnt, 512u * 4);

  // phase 5: out = Xh @ G[b]^T + bp
  gemm_body<true, false, 2, false, false>(
      smem, a.Xh, a.Gh, a.out, nullptr, a.bp,
      8192, 1024, 1024, 2048, bid, 0, 512);
}

// ---------------------------------------------------------------------------
extern "C" void kernel_launch(void* const* d_in, const int* in_sizes, int n_in,
                              void* d_out, int out_size, void* d_ws, size_t ws_size,
                              hipStream_t stream)
{
  const float* x   = (const float*)d_in[0];
  const float* Wq  = (const float*)d_in[1];
  const float* Wk  = (const float*)d_in[2];
  const float* Wv  = (const float*)d_in[3];
  const float* Wp  = (const float*)d_in[4];
  const float* bp  = (const float*)d_in[5];
  const float* bng = (const float*)d_in[6];
  const float* bnb = (const float*)d_in[7];
  const float* bnm = (const float*)d_in[8];
  const float* bnv = (const float*)d_in[9];
  float* out = (float*)d_out;

  char* ws = (char*)d_ws;
  size_t off = 0;
  auto alloc = [&](size_t bytes) {
    char* p = ws + off;
    off += (bytes + 255) & ~(size_t)255;
    return p;
  };
  uint16_t* Xh   = (uint16_t*)alloc((size_t)8192 * 1024 * 2);       // 16MB
  uint16_t* XRh  = (uint16_t*)alloc((size_t)2048 * 1024 * 2);       // 4MB
  uint16_t* Wkvh = (uint16_t*)alloc((size_t)2048 * 1024 * 2);       // 4MB
  uint16_t* Wph  = (uint16_t*)alloc((size_t)1024 * 1024 * 2);       // 2MB
  uint16_t* KVcat= (uint16_t*)alloc((size_t)2 * 2048 * 2048 * 2);   // 16MB (2 bf16 halves)
  uint16_t* Gh   = (uint16_t*)alloc((size_t)4096 * 1024 * 2);       // 8MB
  unsigned* cnt  = (unsigned*)alloc(256);                           // grid barrier
  // overlays (lifetime-disjoint, phases separated by grid barriers):
  // KVcat dead after kv1 phase -> Tth (8MB = first half)
  uint16_t* Tth = KVcat;
  // kv partials (4MB) live only kv1 -> t phase, before GEMM5 writes Gh
  float* KVpart = (float*)Gh;

  // 1) fused prep: x split (hi) + XR pool/BN (hi) + weight splits (hi)
  //    + zero the mono grid-barrier counter
  prep_kernel<<<5120, 256, 0, stream>>>(x, bng, bnb, bnm, bnv, Wk, Wv, Wp,
                                        Xh, XRh, Wkvh, Wph, cnt);
  // 2) everything else in one persistent REGULAR dispatch (4 gaps gone);
  //    all 512 blocks co-resident by construction (2/CU via 64KB LDS +
  //    launch_bounds(256,2); grid = 2 x 256 CUs)
  MonoArgs ma;
  ma.XRh = XRh;   ma.Wkvh = Wkvh; ma.Xh = Xh;  ma.Wph = Wph;
  ma.KVcat = KVcat; ma.Tth = Tth; ma.Gh = Gh;  ma.KVpart = KVpart;
  ma.Wq = Wq;     ma.bp = bp;     ma.out = out; ma.cnt = cnt;
  mono_kernel<<<512, 256, 0, stream>>>(ma);
}

// Round 12
// 377.541 us; speedup vs baseline: 1.1715x; 1.1715x over previous
//
#include <hip/hip_runtime.h>
#include <stdint.h>

#define DEVFN __device__ __forceinline__

typedef __attribute__((ext_vector_type(8))) short s16x8;
typedef __attribute__((ext_vector_type(4))) float f32x4;

DEVFN float bf2f(uint16_t u) {
  union { uint32_t i; float f; } v; v.i = ((uint32_t)u) << 16; return v.f;
}
DEVFN uint16_t f2bf(float f) {
  union { float f; uint32_t i; } v; v.f = f;
  uint32_t u = v.i;
  return (uint16_t)((u + 0x7FFFu + ((u >> 16) & 1u)) >> 16);
}

DEVFN void gload_lds16(const void* g, void* l) {
  __builtin_amdgcn_global_load_lds(
      (const __attribute__((address_space(1))) uint32_t*)g,
      (__attribute__((address_space(3))) uint32_t*)l, 16, 0, 0);
}

// Grid barrier, r12 fix: RELAXED poll (no per-poll cache invalidate!) +
// ONE full fence after exit. r11's ACQUIRE-per-poll emitted buffer_inv
// every ~128cy from every spinning wave -> thrashed L1/L2 under the
// still-working blocks -> 5x slowdown (MfmaUtil 3%). Atomic loads bypass
// L1 and hit the counter's home L2 only; s_sleep(8) ~512cy/poll keeps
// traffic ~1 poll/cy chip-wide. Release = fence before add; acquire =
// single fence after spin exit. Co-residency by construction: 64KB LDS
// -> 2 blocks/CU, launch_bounds(256,2), grid 512 = 2 x 256 CUs.
DEVFN void gbar(unsigned* cnt, unsigned tgt)
{
  __syncthreads();
  if (threadIdx.x == 0) {
    __threadfence();                       // release: prior writes visible
    __hip_atomic_fetch_add(cnt, 1u, __ATOMIC_RELAXED, __HIP_MEMORY_SCOPE_AGENT);
    while (__hip_atomic_load(cnt, __ATOMIC_RELAXED, __HIP_MEMORY_SCOPE_AGENT) < tgt)
      __builtin_amdgcn_s_sleep(8);
  }
  __syncthreads();
  __threadfence();                         // acquire ONCE: inv stale caches
}

// ---------------------------------------------------------------------------
// Fused prep: blocks 0..2047  : x -> Xh (hi) + XR = BN(AvgPool4) hi ONLY
//             blocks 2048..5119: Wk/Wv -> Wkvh (hi), Wp -> Wph (hi)
// Also zeroes the mono-kernel grid-barrier counter (block 0 thread 0).
// ---------------------------------------------------------------------------
__global__ __launch_bounds__(256)
void prep_kernel(const float* __restrict__ x,
                 const float* __restrict__ bn_g, const float* __restrict__ bn_b,
                 const float* __restrict__ bn_m, const float* __restrict__ bn_v,
                 const float* __restrict__ Wk, const float* __restrict__ Wv,
                 const float* __restrict__ Wp,
                 uint16_t* __restrict__ Xh,
                 uint16_t* __restrict__ XRh,
                 uint16_t* __restrict__ Wkvh,
                 uint16_t* __restrict__ Wph,
                 unsigned* __restrict__ cnt)
{
  const int t = threadIdx.x;
  const int bid = blockIdx.x;
  if (bid == 0 && t == 0) *cnt = 0;          // reset mono barrier counter
  if (bid < 2048) {
    const int prow = bid;                    // pooled row: b*512 + mm
    const int c0 = t * 4;
    const size_t xbase = (size_t)prow * 4096 + c0;   // x row prow*4
    float s[4] = {0.f, 0.f, 0.f, 0.f};
#pragma unroll
    for (int r = 0; r < 4; ++r) {
      const float4 w = *(const float4*)(x + xbase + (size_t)r * 1024);
      const float vv[4] = { w.x, w.y, w.z, w.w };
      uint64_t wh = 0;
#pragma unroll
      for (int j = 0; j < 4; ++j) {
        wh |= ((uint64_t)f2bf(vv[j])) << (16 * j);
        s[j] += vv[j];
      }
      *(uint64_t*)(Xh + xbase + (size_t)r * 1024) = wh;
    }
    uint64_t wh = 0;
#pragma unroll
    for (int j = 0; j < 4; ++j) {
      const int c = c0 + j;
      const float y = (s[j] * 0.25f - bn_m[c]) / sqrtf(bn_v[c] + 1e-6f) * bn_g[c] + bn_b[c];
      wh |= ((uint64_t)f2bf(y)) << (16 * j);
    }
    *(uint64_t*)(XRh + (size_t)prow * 1024 + c0) = wh;
  } else {
    const int wb = bid - 2048;               // 0..3071
    const int which = wb >> 10;
    const int i = (wb & 1023) * 256 + t;     // float4 index
    const float* src = (which == 0) ? Wk : (which == 1) ? Wv : Wp;
    const float4 v = ((const float4*)src)[i];
    const float vv[4] = { v.x, v.y, v.z, v.w };
    uint64_t wh = 0;
#pragma unroll
    for (int j = 0; j < 4; ++j)
      wh |= ((uint64_t)f2bf(vv[j])) << (16 * j);
    if (which == 2) {
      ((uint64_t*)Wph)[i] = wh;
    } else {
      ((uint64_t*)Wkvh)[(size_t)which * (1024 * 1024 / 4) + i] = wh;
    }
  }
}

// ---------------------------------------------------------------------------
// NT GEMM phase body — byte-for-byte the r6 champion (measured 85.47):
// single LDS buffer, BK=128, 16x16x32 MFMA, register-frontload reorder.
// blockIdx/gridDim are parameters so it can run inside the mono kernel.
// ---------------------------------------------------------------------------
template<bool BATCHB, bool AMODA, int EPI, bool KSPLIT2, bool SMALLM>
DEVFN void gemm_body(char* smem,
                     const uint16_t* __restrict__ A0,
                     const uint16_t* __restrict__ B0,
                     float* __restrict__ C32, uint16_t* __restrict__ Cb0,
                     const float* __restrict__ bias,
                     int M, int N, int K, int rows_per_batch,
                     int bidx, int bidy, int nwg)
{
  constexpr int BM = SMALLM ? 64 : 128, BN = 128, BK = 128;
  constexpr int WCN = SMALLM ? 4 : 2;         // waves along N
  constexpr int WNW = BN / WCN;               // per-wave N width (32 or 64)
  constexpr int NREP = WNW / 16;              // 2 or 4
  constexpr int APASS = SMALLM ? 4 : 8;       // A staging passes (4KB each)
  constexpr int BPASS = 8;                    // B staging passes
  uint16_t* sA = (uint16_t*)smem;
  uint16_t* sB = (uint16_t*)(smem + (size_t)BM * BK * 2);

  const int t = threadIdx.x;
  const int lane = t & 63;
  const int wave = t >> 6;
  const int wr = wave / WCN, wc = wave % WCN;
  const int fq = lane >> 4, fr = lane & 15;

  // T1: XCD-chunked swizzle (nwg divisible by 8 for all our grids)
  const int cpx = nwg >> 3;
  const int orig = bidx;
  const int swz = (orig & 7) * cpx + (orig >> 3);
  const int nbx = N >> 7;
  const int bm = (swz / nbx) * BM;
  const int bn = (swz % nbx) * BN;

  const uint16_t* Ap = A0;
  const uint16_t* Bp = B0;
  if (BATCHB)
    Bp += (size_t)(bm / rows_per_batch) * (size_t)N * (size_t)K;
  if (KSPLIT2) {
    const size_t half = (size_t)bidy * M * N;
    if (EPI == 1) Cb0 += half; else C32 += half;
  }

  f32x4 acc[4][NREP];
#pragma unroll
  for (int m = 0; m < 4; ++m)
#pragma unroll
    for (int n = 0; n < NREP; ++n) acc[m][n] = (f32x4)0.0f;

  auto STAGE = [&](int kt) {
#pragma unroll
    for (int i = 0; i < APASS; ++i) {
      const int X = t * 16 + i * 4096;          // linear LDS byte dest
      const int r = X >> 8;                     // row (256B per row)
      const int g = ((X >> 4) & 15) ^ (r & 7);  // pre-swizzled source slot
      const int kcol = (kt << 7) + g * 8;
      const int arow = AMODA ? ((bm + r) & 1023) : (bm + r);
      gload_lds16(Ap + (size_t)arow * K + kcol, (char*)sA + X);
    }
#pragma unroll
    for (int i = 0; i < BPASS; ++i) {
      const int X = t * 16 + i * 4096;
      const int r = X >> 8;
      const int g = ((X >> 4) & 15) ^ (r & 7);
      const int kcol = (kt << 7) + g * 8;
      gload_lds16(Bp + (size_t)(bn + r) * K + kcol, (char*)sB + X);
    }
  };

  const int nkt = K >> (KSPLIT2 ? 8 : 7);
  const int kt0 = KSPLIT2 ? (bidy * nkt) : 0;
  const int ktend = kt0 + nkt;

  STAGE(kt0);                                  // prologue prefetch
  for (int kt = kt0; kt < ktend; ++kt) {
    // drains this wave's staging loads (vmcnt 0) + barrier: tile kt ready
    __syncthreads();

    // front-load the whole tile's fragments into registers
    s16x8 av[4][4], bv[4][NREP];               // [ks][.]
#pragma unroll
    for (int ks = 0; ks < 4; ++ks) {
#pragma unroll
      for (int m = 0; m < 4; ++m) {
        const int ra = wr * 64 + m * 16 + fr;
        const int offA = ra * 256 + ((((ks << 2) + fq) ^ (ra & 7)) << 4);
        av[ks][m] = *(const s16x8*)((const char*)sA + offA);
      }
#pragma unroll
      for (int n = 0; n < NREP; ++n) {
        const int rb = wc * WNW + n * 16 + fr;
        const int offB = rb * 256 + ((((ks << 2) + fq) ^ (rb & 7)) << 4);
        bv[ks][n] = *(const s16x8*)((const char*)sB + offB);
      }
    }

    // lgkm drained by syncthreads; LDS buffer dead -> overwrite it early
    __syncthreads();
    if (kt + 1 < ktend) STAGE(kt + 1);

    // MFMA phase on registers (latency cover for kt+1's loads)
#pragma unroll
    for (int ks = 0; ks < 4; ++ks)
#pragma unroll
      for (int m = 0; m < 4; ++m)
#pragma unroll
        for (int n = 0; n < NREP; ++n)
          acc[m][n] = __builtin_amdgcn_mfma_f32_16x16x32_bf16(
              av[ks][m], bv[ks][n], acc[m][n], 0, 0, 0);
  }

  // epilogue: C/D layout col = lane&15, row = (lane>>4)*4 + reg (m89/m91)
#pragma unroll
  for (int m = 0; m < 4; ++m) {
#pragma unroll
    for (int n = 0; n < NREP; ++n) {
#pragma unroll
      for (int j = 0; j < 4; ++j) {
        const int row = bm + wr * 64 + m * 16 + fq * 4 + j;
        const int col = bn + wc * WNW + n * 16 + fr;
        const size_t idx = (size_t)row * N + col;
        float v = acc[m][n][j];
        if constexpr (EPI == 0) {
          C32[idx] = v;
        } else if constexpr (EPI == 1) {
          Cb0[idx] = f2bf(v);
        } else {
          C32[idx] = v + bias[col];
        }
      }
    }
  }
}

// ---------------------------------------------------------------------------
// kv1 phase body (r6 kv1_kernel): partial[wid][f][e] = sum_64rows K*V.
// KVcat bf16 in TWO split-K halves; summed fp32 on stage. wid = bh*8+ch.
// Leading __syncthreads so back-to-back calls can reuse the LDS arena.
// ---------------------------------------------------------------------------
DEVFN void kv1_body(char* smem, const uint16_t* __restrict__ KVcat,
                    float* __restrict__ part, int wid)
{
  float (*sK)[32] = (float(*)[32])smem;
  float (*sV)[32] = (float(*)[32])(smem + 8192);
  const int bh = wid >> 3, ch = wid & 7;
  const int b = bh >> 5, h = bh & 31;
  const int t = threadIdx.x;
  const int f = t >> 3, e0 = (t & 7) * 4;
  const int lr = t >> 2, q = t & 3;
  const size_t rowb = (size_t)(b * 512 + ch * 64 + lr) * 2048 + h * 32 + q * 8;
  const size_t H = (size_t)2048 * 2048;   // second split-K half offset
  const s16x8 k0 = *(const s16x8*)(KVcat + rowb);
  const s16x8 k1 = *(const s16x8*)(KVcat + H + rowb);
  const s16x8 v0 = *(const s16x8*)(KVcat + rowb + 1024);
  const s16x8 v1 = *(const s16x8*)(KVcat + H + rowb + 1024);
  __syncthreads();                         // prior users of smem done
#pragma unroll
  for (int j = 0; j < 8; ++j) {
    sK[lr][q * 8 + j] = bf2f((uint16_t)k0[j]) + bf2f((uint16_t)k1[j]);
    sV[lr][q * 8 + j] = bf2f((uint16_t)v0[j]) + bf2f((uint16_t)v1[j]);
  }
  __syncthreads();
  float a0 = 0.f, a1 = 0.f, a2 = 0.f, a3 = 0.f;
#pragma unroll 16
  for (int mm = 0; mm < 64; ++mm) {
    const float kf = sK[mm][f];
    const float4 vv = *(const float4*)&sV[mm][e0];
    a0 += kf * vv.x; a1 += kf * vv.y; a2 += kf * vv.z; a3 += kf * vv.w;
  }
  float* o = part + ((size_t)wid * 32 + f) * 32 + e0;
  o[0] = a0; o[1] = a1; o[2] = a2; o[3] = a3;
}

// ---------------------------------------------------------------------------
// t phase body (r6 t_kernel): KV[b,h] = scale * sum_ch part;
// Tt[b][c][h*32+e] = sum_f KV[f][e] * Wq[h*32+f, c]  (bf16 hi out)
// ---------------------------------------------------------------------------
DEVFN void t_body(char* smem, const float* __restrict__ part,
                  const float* __restrict__ Wq, uint16_t* __restrict__ Tth,
                  int bid)
{
  float (*sKV)[32] = (float(*)[32])smem;   // [f][e]
  const int b = bid >> 7, h = (bid >> 2) & 31, cc = bid & 3;
  const int bh = b * 32 + h;
  const int t = threadIdx.x;
  {
    const int f = t >> 3, e0 = (t & 7) * 4;
    f32x4 a = (f32x4)0.0f;
#pragma unroll
    for (int ch = 0; ch < 8; ++ch)
      a += *(const f32x4*)(part + ((size_t)(bh * 8 + ch) * 32 + f) * 32 + e0);
    a *= 0.17677669529663687f;       // 1/sqrt(32)
    *(f32x4*)&sKV[f][e0] = a;
  }
  __syncthreads();
  const int c = cc * 256 + t;
  f32x4 acc[8];
#pragma unroll
  for (int i = 0; i < 8; ++i) acc[i] = (f32x4)0.0f;
  const float* wqp = Wq + (size_t)(h * 32) * 1024 + c;
#pragma unroll 8
  for (int f = 0; f < 32; ++f) {
    const float wq = wqp[(size_t)f * 1024];
#pragma unroll
    for (int i = 0; i < 8; ++i) {
      const f32x4 kv = *(const f32x4*)&sKV[f][i * 4];
      acc[i] += kv * wq;
    }
  }
  const size_t o = (((size_t)b << 10) + c) * 1024 + h * 32;
#pragma unroll
  for (int i = 0; i < 8; ++i) {
    uint64_t wh = 0;
#pragma unroll
    for (int j = 0; j < 4; ++j)
      wh |= ((uint64_t)f2bf(acc[i][j])) << (16 * j);
    *(uint64_t*)(Tth + o + i * 4) = wh;
  }
}

// ---------------------------------------------------------------------------
// Mono kernel: GEMM2 + kv1 + t + GEMM5 + GEMM6 in ONE regular dispatch,
// grid barriers between phases (r12: relaxed-poll barrier). 512 blocks x
// 256 threads, 64KB LDS -> exactly 2 blocks/CU -> all blocks resident.
// Phase bodies identical to the r6 champion.
// ---------------------------------------------------------------------------
struct MonoArgs {
  const uint16_t* XRh; const uint16_t* Wkvh;
  const uint16_t* Xh;  const uint16_t* Wph;
  uint16_t* KVcat; uint16_t* Tth; uint16_t* Gh; float* KVpart;
  const float* Wq; const float* bp; float* out;
  unsigned* cnt;
};

__global__ __launch_bounds__(256, 2)
void mono_kernel(MonoArgs a)
{
  __shared__ __align__(16) char smem[65536];
  const int bid = blockIdx.x;                // 0..511

  // phase 1: [K|V] GEMM, split-K x2 (r6 GEMM2; x = bid&255, y = bid>>8)
  gemm_body<false, false, 1, true, false>(
      smem, a.XRh, a.Wkvh, nullptr, a.KVcat, nullptr,
      2048, 2048, 1024, 1 << 30, bid & 255, bid >> 8, 256);
  gbar(a.cnt, 512u * 1);

  // phase 2: KV partials (1024 works -> 2 per block)
  kv1_body(smem, a.KVcat, a.KVpart, bid * 2);
  kv1_body(smem, a.KVcat, a.KVpart, bid * 2 + 1);
  gbar(a.cnt, 512u * 2);

  // phase 3: Tt = (blockdiag(KV)^T Wq)^T
  t_body(smem, a.KVpart, a.Wq, a.Tth, bid);
  gbar(a.cnt, 512u * 3);

  // phase 4: G[b] = Wph @ Tt[b]^T (SMALLM)
  gemm_body<true, true, 1, false, true>(
      smem, a.Wph, a.Tth, nullptr, a.Gh, nullptr,
      4096, 1024, 1024, 1024, bid, 0, 512);
  gbar(a.cnt, 512u * 4);

  // phase 5: out = Xh @ G[b]^T + bp
  gemm_body<true, false, 2, false, false>(
      smem, a.Xh, a.Gh, a.out, nullptr, a.bp,
      8192, 1024, 1024, 2048, bid, 0, 512);
}

// ---------------------------------------------------------------------------
extern "C" void kernel_launch(void* const* d_in, const int* in_sizes, int n_in,
                              void* d_out, int out_size, void* d_ws, size_t ws_size,
                              hipStream_t stream)
{
  const float* x   = (const float*)d_in[0];
  const float* Wq  = (const float*)d_in[1];
  const float* Wk  = (const float*)d_in[2];
  const float* Wv  = (const float*)d_in[3];
  const float* Wp  = (const float*)d_in[4];
  const float* bp  = (const float*)d_in[5];
  const float* bng = (const float*)d_in[6];
  const float* bnb = (const float*)d_in[7];
  const float* bnm = (const float*)d_in[8];
  const float* bnv = (const float*)d_in[9];
  float* out = (float*)d_out;

  char* ws = (char*)d_ws;
  size_t off = 0;
  auto alloc = [&](size_t bytes) {
    char* p = ws + off;
    off += (bytes + 255) & ~(size_t)255;
    return p;
  };
  uint16_t* Xh   = (uint16_t*)alloc((size_t)8192 * 1024 * 2);       // 16MB
  uint16_t* XRh  = (uint16_t*)alloc((size_t)2048 * 1024 * 2);       // 4MB
  uint16_t* Wkvh = (uint16_t*)alloc((size_t)2048 * 1024 * 2);       // 4MB
  uint16_t* Wph  = (uint16_t*)alloc((size_t)1024 * 1024 * 2);       // 2MB
  uint16_t* KVcat= (uint16_t*)alloc((size_t)2 * 2048 * 2048 * 2);   // 16MB (2 bf16 halves)
  uint16_t* Gh   = (uint16_t*)alloc((size_t)4096 * 1024 * 2);       // 8MB
  unsigned* cnt  = (unsigned*)alloc(256);                           // grid barrier
  // overlays (lifetime-disjoint, phases separated by grid barriers):
  // KVcat dead after kv1 phase -> Tth (8MB = first half)
  uint16_t* Tth = KVcat;
  // kv partials (4MB) live only kv1 -> t phase, before GEMM5 writes Gh
  float* KVpart = (float*)Gh;

  // 1) fused prep: x split (hi) + XR pool/BN (hi) + weight splits (hi)
  //    + zero the mono grid-barrier counter
  prep_kernel<<<5120, 256, 0, stream>>>(x, bng, bnb, bnm, bnv, Wk, Wv, Wp,
                                        Xh, XRh, Wkvh, Wph, cnt);
  // 2) everything else in one persistent regular dispatch (4 gaps gone);
  //    all 512 blocks co-resident by construction
  MonoArgs ma;
  ma.XRh = XRh;   ma.Wkvh = Wkvh; ma.Xh = Xh;  ma.Wph = Wph;
  ma.KVcat = KVcat; ma.Tth = Tth; ma.Gh = Gh;  ma.KVpart = KVpart;
  ma.Wq = Wq;     ma.bp = bp;     ma.out = out; ma.cnt = cnt;
  mono_kernel<<<512, 256, 0, stream>>>(ma);
}

// Round 13
// 104.538 us; speedup vs baseline: 4.2310x; 3.6115x over previous
//
#include <hip/hip_runtime.h>
#include <stdint.h>

#define DEVFN __device__ __forceinline__

typedef __attribute__((ext_vector_type(8))) short s16x8;
typedef __attribute__((ext_vector_type(4))) float f32x4;

DEVFN float bf2f(uint16_t u) {
  union { uint32_t i; float f; } v; v.i = ((uint32_t)u) << 16; return v.f;
}
DEVFN uint16_t f2bf(float f) {
  union { float f; uint32_t i; } v; v.f = f;
  uint32_t u = v.i;
  return (uint16_t)((u + 0x7FFFu + ((u >> 16) & 1u)) >> 16);
}

DEVFN void gload_lds16(const void* g, void* l) {
  __builtin_amdgcn_global_load_lds(
      (const __attribute__((address_space(1))) uint32_t*)g,
      (__attribute__((address_space(3))) uint32_t*)l, 16, 0, 0);
}

// ---------------------------------------------------------------------------
// Hierarchical grid barrier (r13). r11/r12 post-mortem: the cost was the
// FENCE STORM — 2048+512 full __threadfence() per barrier, each emitting
// buffer_wbl2 (write back the ENTIRE XCD L2) -> ~2560 wbl2 serialized at 8
// L2s ~ 80us/barrier. Architectural minimum: ONE wbl2 per XCD (release:
// when all 64 of an XCD's blocks arrived, their stores are complete in the
// shared per-XCD L2 -> the last arriver flushes once) + one cheap
// buffer_inv per block (acquire: inv own L1 + stale L2 lines; required for
// the buffer overlays). Capacity argument: 512 blocks = 2/CU x 32 CU/XCD
// x 8 XCD -> exactly 64 blocks per XCD, all co-resident (64KB LDS +
// waves_per_eu(2,2) cap at 2 blocks/CU).
// cnt layout: cnt[x*64] = XCD x arrival (monotonic), cnt[512] = global.
// ---------------------------------------------------------------------------
DEVFN void gbar(unsigned* cnt, unsigned xcc, unsigned gtgt)
{
  __syncthreads();                      // all waves: stores complete (vmcnt 0)
  if (threadIdx.x == 0) {
    const unsigned old = __hip_atomic_fetch_add(
        cnt + (xcc << 6), 1u, __ATOMIC_RELAXED, __HIP_MEMORY_SCOPE_AGENT);
    if ((old & 63) == 63) {             // last of this XCD's 64 blocks
      __threadfence();                  // ONE wbl2 per XCD: publish its L2
      __hip_atomic_fetch_add(cnt + 512, 1u,
                             __ATOMIC_RELAXED, __HIP_MEMORY_SCOPE_AGENT);
    }
    while (__hip_atomic_load(cnt + 512, __ATOMIC_RELAXED,
                             __HIP_MEMORY_SCOPE_AGENT) < gtgt)
      __builtin_amdgcn_s_sleep(32);
    // acquire: inv L1 + stale (non-owned) L2 lines, wait for completion
    asm volatile("buffer_inv sc0 sc1\n\ts_waitcnt vmcnt(0)" ::: "memory");
  }
  __syncthreads();
}

// ---------------------------------------------------------------------------
// Fused prep: blocks 0..2047  : x -> Xh (hi) + XR = BN(AvgPool4) hi ONLY
//             blocks 2048..5119: Wk/Wv -> Wkvh (hi), Wp -> Wph (hi)
// Also zeroes the 9 barrier counters (block 0, threads 0..8).
// ---------------------------------------------------------------------------
__global__ __launch_bounds__(256)
void prep_kernel(const float* __restrict__ x,
                 const float* __restrict__ bn_g, const float* __restrict__ bn_b,
                 const float* __restrict__ bn_m, const float* __restrict__ bn_v,
                 const float* __restrict__ Wk, const float* __restrict__ Wv,
                 const float* __restrict__ Wp,
                 uint16_t* __restrict__ Xh,
                 uint16_t* __restrict__ XRh,
                 uint16_t* __restrict__ Wkvh,
                 uint16_t* __restrict__ Wph,
                 unsigned* __restrict__ cnt)
{
  const int t = threadIdx.x;
  const int bid = blockIdx.x;
  if (bid == 0 && t < 9) cnt[t * 64] = 0;  // reset 8 XCD + 1 global counter
  if (bid < 2048) {
    const int prow = bid;                    // pooled row: b*512 + mm
    const int c0 = t * 4;
    const size_t xbase = (size_t)prow * 4096 + c0;   // x row prow*4
    float s[4] = {0.f, 0.f, 0.f, 0.f};
#pragma unroll
    for (int r = 0; r < 4; ++r) {
      const float4 w = *(const float4*)(x + xbase + (size_t)r * 1024);
      const float vv[4] = { w.x, w.y, w.z, w.w };
      uint64_t wh = 0;
#pragma unroll
      for (int j = 0; j < 4; ++j) {
        wh |= ((uint64_t)f2bf(vv[j])) << (16 * j);
        s[j] += vv[j];
      }
      *(uint64_t*)(Xh + xbase + (size_t)r * 1024) = wh;
    }
    uint64_t wh = 0;
#pragma unroll
    for (int j = 0; j < 4; ++j) {
      const int c = c0 + j;
      const float y = (s[j] * 0.25f - bn_m[c]) / sqrtf(bn_v[c] + 1e-6f) * bn_g[c] + bn_b[c];
      wh |= ((uint64_t)f2bf(y)) << (16 * j);
    }
    *(uint64_t*)(XRh + (size_t)prow * 1024 + c0) = wh;
  } else {
    const int wb = bid - 2048;               // 0..3071
    const int which = wb >> 10;
    const int i = (wb & 1023) * 256 + t;     // float4 index
    const float* src = (which == 0) ? Wk : (which == 1) ? Wv : Wp;
    const float4 v = ((const float4*)src)[i];
    const float vv[4] = { v.x, v.y, v.z, v.w };
    uint64_t wh = 0;
#pragma unroll
    for (int j = 0; j < 4; ++j)
      wh |= ((uint64_t)f2bf(vv[j])) << (16 * j);
    if (which == 2) {
      ((uint64_t*)Wph)[i] = wh;
    } else {
      ((uint64_t*)Wkvh)[(size_t)which * (1024 * 1024 / 4) + i] = wh;
    }
  }
}

// ---------------------------------------------------------------------------
// NT GEMM phase body — byte-for-byte the r6 champion (measured 85.47):
// single LDS buffer, BK=128, 16x16x32 MFMA, register-frontload reorder.
// blockIdx/gridDim are parameters so it can run inside the mono kernel.
// ---------------------------------------------------------------------------
template<bool BATCHB, bool AMODA, int EPI, bool KSPLIT2, bool SMALLM>
DEVFN void gemm_body(char* smem,
                     const uint16_t* __restrict__ A0,
                     const uint16_t* __restrict__ B0,
                     float* __restrict__ C32, uint16_t* __restrict__ Cb0,
                     const float* __restrict__ bias,
                     int M, int N, int K, int rows_per_batch,
                     int bidx, int bidy, int nwg)
{
  constexpr int BM = SMALLM ? 64 : 128, BN = 128, BK = 128;
  constexpr int WCN = SMALLM ? 4 : 2;         // waves along N
  constexpr int WNW = BN / WCN;               // per-wave N width (32 or 64)
  constexpr int NREP = WNW / 16;              // 2 or 4
  constexpr int APASS = SMALLM ? 4 : 8;       // A staging passes (4KB each)
  constexpr int BPASS = 8;                    // B staging passes
  uint16_t* sA = (uint16_t*)smem;
  uint16_t* sB = (uint16_t*)(smem + (size_t)BM * BK * 2);

  const int t = threadIdx.x;
  const int lane = t & 63;
  const int wave = t >> 6;
  const int wr = wave / WCN, wc = wave % WCN;
  const int fq = lane >> 4, fr = lane & 15;

  // T1: XCD-chunked swizzle (nwg divisible by 8 for all our grids)
  const int cpx = nwg >> 3;
  const int orig = bidx;
  const int swz = (orig & 7) * cpx + (orig >> 3);
  const int nbx = N >> 7;
  const int bm = (swz / nbx) * BM;
  const int bn = (swz % nbx) * BN;

  const uint16_t* Ap = A0;
  const uint16_t* Bp = B0;
  if (BATCHB)
    Bp += (size_t)(bm / rows_per_batch) * (size_t)N * (size_t)K;
  if (KSPLIT2) {
    const size_t half = (size_t)bidy * M * N;
    if (EPI == 1) Cb0 += half; else C32 += half;
  }

  f32x4 acc[4][NREP];
#pragma unroll
  for (int m = 0; m < 4; ++m)
#pragma unroll
    for (int n = 0; n < NREP; ++n) acc[m][n] = (f32x4)0.0f;

  auto STAGE = [&](int kt) {
#pragma unroll
    for (int i = 0; i < APASS; ++i) {
      const int X = t * 16 + i * 4096;          // linear LDS byte dest
      const int r = X >> 8;                     // row (256B per row)
      const int g = ((X >> 4) & 15) ^ (r & 7);  // pre-swizzled source slot
      const int kcol = (kt << 7) + g * 8;
      const int arow = AMODA ? ((bm + r) & 1023) : (bm + r);
      gload_lds16(Ap + (size_t)arow * K + kcol, (char*)sA + X);
    }
#pragma unroll
    for (int i = 0; i < BPASS; ++i) {
      const int X = t * 16 + i * 4096;
      const int r = X >> 8;
      const int g = ((X >> 4) & 15) ^ (r & 7);
      const int kcol = (kt << 7) + g * 8;
      gload_lds16(Bp + (size_t)(bn + r) * K + kcol, (char*)sB + X);
    }
  };

  const int nkt = K >> (KSPLIT2 ? 8 : 7);
  const int kt0 = KSPLIT2 ? (bidy * nkt) : 0;
  const int ktend = kt0 + nkt;

  STAGE(kt0);                                  // prologue prefetch
  for (int kt = kt0; kt < ktend; ++kt) {
    // drains this wave's staging loads (vmcnt 0) + barrier: tile kt ready
    __syncthreads();

    // front-load the whole tile's fragments into registers
    s16x8 av[4][4], bv[4][NREP];               // [ks][.]
#pragma unroll
    for (int ks = 0; ks < 4; ++ks) {
#pragma unroll
      for (int m = 0; m < 4; ++m) {
        const int ra = wr * 64 + m * 16 + fr;
        const int offA = ra * 256 + ((((ks << 2) + fq) ^ (ra & 7)) << 4);
        av[ks][m] = *(const s16x8*)((const char*)sA + offA);
      }
#pragma unroll
      for (int n = 0; n < NREP; ++n) {
        const int rb = wc * WNW + n * 16 + fr;
        const int offB = rb * 256 + ((((ks << 2) + fq) ^ (rb & 7)) << 4);
        bv[ks][n] = *(const s16x8*)((const char*)sB + offB);
      }
    }

    // lgkm drained by syncthreads; LDS buffer dead -> overwrite it early
    __syncthreads();
    if (kt + 1 < ktend) STAGE(kt + 1);

    // MFMA phase on registers (latency cover for kt+1's loads)
#pragma unroll
    for (int ks = 0; ks < 4; ++ks)
#pragma unroll
      for (int m = 0; m < 4; ++m)
#pragma unroll
        for (int n = 0; n < NREP; ++n)
          acc[m][n] = __builtin_amdgcn_mfma_f32_16x16x32_bf16(
              av[ks][m], bv[ks][n], acc[m][n], 0, 0, 0);
  }

  // epilogue: C/D layout col = lane&15, row = (lane>>4)*4 + reg (m89/m91)
#pragma unroll
  for (int m = 0; m < 4; ++m) {
#pragma unroll
    for (int n = 0; n < NREP; ++n) {
#pragma unroll
      for (int j = 0; j < 4; ++j) {
        const int row = bm + wr * 64 + m * 16 + fq * 4 + j;
        const int col = bn + wc * WNW + n * 16 + fr;
        const size_t idx = (size_t)row * N + col;
        float v = acc[m][n][j];
        if constexpr (EPI == 0) {
          C32[idx] = v;
        } else if constexpr (EPI == 1) {
          Cb0[idx] = f2bf(v);
        } else {
          C32[idx] = v + bias[col];
        }
      }
    }
  }
}

// ---------------------------------------------------------------------------
// kv1 phase body (r6 kv1_kernel): partial[wid][f][e] = sum_64rows K*V.
// KVcat bf16 in TWO split-K halves; summed fp32 on stage. wid = bh*8+ch.
// Leading __syncthreads so back-to-back calls can reuse the LDS arena.
// ---------------------------------------------------------------------------
DEVFN void kv1_body(char* smem, const uint16_t* __restrict__ KVcat,
                    float* __restrict__ part, int wid)
{
  float (*sK)[32] = (float(*)[32])smem;
  float (*sV)[32] = (float(*)[32])(smem + 8192);
  const int bh = wid >> 3, ch = wid & 7;
  const int b = bh >> 5, h = bh & 31;
  const int t = threadIdx.x;
  const int f = t >> 3, e0 = (t & 7) * 4;
  const int lr = t >> 2, q = t & 3;
  const size_t rowb = (size_t)(b * 512 + ch * 64 + lr) * 2048 + h * 32 + q * 8;
  const size_t H = (size_t)2048 * 2048;   // second split-K half offset
  const s16x8 k0 = *(const s16x8*)(KVcat + rowb);
  const s16x8 k1 = *(const s16x8*)(KVcat + H + rowb);
  const s16x8 v0 = *(const s16x8*)(KVcat + rowb + 1024);
  const s16x8 v1 = *(const s16x8*)(KVcat + H + rowb + 1024);
  __syncthreads();                         // prior users of smem done
#pragma unroll
  for (int j = 0; j < 8; ++j) {
    sK[lr][q * 8 + j] = bf2f((uint16_t)k0[j]) + bf2f((uint16_t)k1[j]);
    sV[lr][q * 8 + j] = bf2f((uint16_t)v0[j]) + bf2f((uint16_t)v1[j]);
  }
  __syncthreads();
  float a0 = 0.f, a1 = 0.f, a2 = 0.f, a3 = 0.f;
#pragma unroll 16
  for (int mm = 0; mm < 64; ++mm) {
    const float kf = sK[mm][f];
    const float4 vv = *(const float4*)&sV[mm][e0];
    a0 += kf * vv.x; a1 += kf * vv.y; a2 += kf * vv.z; a3 += kf * vv.w;
  }
  float* o = part + ((size_t)wid * 32 + f) * 32 + e0;
  o[0] = a0; o[1] = a1; o[2] = a2; o[3] = a3;
}

// ---------------------------------------------------------------------------
// t phase body (r6 t_kernel): KV[b,h] = scale * sum_ch part;
// Tt[b][c][h*32+e] = sum_f KV[f][e] * Wq[h*32+f, c]  (bf16 hi out)
// ---------------------------------------------------------------------------
DEVFN void t_body(char* smem, const float* __restrict__ part,
                  const float* __restrict__ Wq, uint16_t* __restrict__ Tth,
                  int bid)
{
  float (*sKV)[32] = (float(*)[32])smem;   // [f][e]
  const int b = bid >> 7, h = (bid >> 2) & 31, cc = bid & 3;
  const int bh = b * 32 + h;
  const int t = threadIdx.x;
  {
    const int f = t >> 3, e0 = (t & 7) * 4;
    f32x4 a = (f32x4)0.0f;
#pragma unroll
    for (int ch = 0; ch < 8; ++ch)
      a += *(const f32x4*)(part + ((size_t)(bh * 8 + ch) * 32 + f) * 32 + e0);
    a *= 0.17677669529663687f;       // 1/sqrt(32)
    *(f32x4*)&sKV[f][e0] = a;
  }
  __syncthreads();
  const int c = cc * 256 + t;
  f32x4 acc[8];
#pragma unroll
  for (int i = 0; i < 8; ++i) acc[i] = (f32x4)0.0f;
  const float* wqp = Wq + (size_t)(h * 32) * 1024 + c;
#pragma unroll 8
  for (int f = 0; f < 32; ++f) {
    const float wq = wqp[(size_t)f * 1024];
#pragma unroll
    for (int i = 0; i < 8; ++i) {
      const f32x4 kv = *(const f32x4*)&sKV[f][i * 4];
      acc[i] += kv * wq;
    }
  }
  const size_t o = (((size_t)b << 10) + c) * 1024 + h * 32;
#pragma unroll
  for (int i = 0; i < 8; ++i) {
    uint64_t wh = 0;
#pragma unroll
    for (int j = 0; j < 4; ++j)
      wh |= ((uint64_t)f2bf(acc[i][j])) << (16 * j);
    *(uint64_t*)(Tth + o + i * 4) = wh;
  }
}

// ---------------------------------------------------------------------------
// Mono kernel (r13): GEMM2 + kv1 + t + GEMM5 + GEMM6 in ONE regular
// dispatch with the hierarchical barrier (8 wbl2 + 512 inv per barrier
// instead of 2560 full fences). waves_per_eu(2,2) pins the VGPR budget
// at 256 (r11/r12's 120 VGPR starved the frontload -> spill); LDS 64KB
// caps at 2 blocks/CU anyway, so nothing is lost.
// ---------------------------------------------------------------------------
struct MonoArgs {
  const uint16_t* XRh; const uint16_t* Wkvh;
  const uint16_t* Xh;  const uint16_t* Wph;
  uint16_t* KVcat; uint16_t* Tth; uint16_t* Gh; float* KVpart;
  const float* Wq; const float* bp; float* out;
  unsigned* cnt;
};

__global__ __launch_bounds__(256)
__attribute__((amdgpu_waves_per_eu(2, 2)))
void mono_kernel(MonoArgs a)
{
  __shared__ __align__(16) char smem[65536];
  const int bid = blockIdx.x;                // 0..511
  unsigned xcc;
  asm("s_getreg_b32 %0, hwreg(HW_REG_XCC_ID)" : "=s"(xcc));
  xcc &= 7;

  // phase 1: [K|V] GEMM, split-K x2 (r6 GEMM2; x = bid&255, y = bid>>8)
  gemm_body<false, false, 1, true, false>(
      smem, a.XRh, a.Wkvh, nullptr, a.KVcat, nullptr,
      2048, 2048, 1024, 1 << 30, bid & 255, bid >> 8, 256);
  gbar(a.cnt, xcc, 8u * 1);

  // phase 2: KV partials (1024 works -> 2 per block)
  kv1_body(smem, a.KVcat, a.KVpart, bid * 2);
  kv1_body(smem, a.KVcat, a.KVpart, bid * 2 + 1);
  gbar(a.cnt, xcc, 8u * 2);

  // phase 3: Tt = (blockdiag(KV)^T Wq)^T
  t_body(smem, a.KVpart, a.Wq, a.Tth, bid);
  gbar(a.cnt, xcc, 8u * 3);

  // phase 4: G[b] = Wph @ Tt[b]^T (SMALLM)
  gemm_body<true, true, 1, false, true>(
      smem, a.Wph, a.Tth, nullptr, a.Gh, nullptr,
      4096, 1024, 1024, 1024, bid, 0, 512);
  gbar(a.cnt, xcc, 8u * 4);

  // phase 5: out = Xh @ G[b]^T + bp
  gemm_body<true, false, 2, false, false>(
      smem, a.Xh, a.Gh, a.out, nullptr, a.bp,
      8192, 1024, 1024, 2048, bid, 0, 512);
}

// ---------------------------------------------------------------------------
extern "C" void kernel_launch(void* const* d_in, const int* in_sizes, int n_in,
                              void* d_out, int out_size, void* d_ws, size_t ws_size,
                              hipStream_t stream)
{
  const float* x   = (const float*)d_in[0];
  const float* Wq  = (const float*)d_in[1];
  const float* Wk  = (const float*)d_in[2];
  const float* Wv  = (const float*)d_in[3];
  const float* Wp  = (const float*)d_in[4];
  const float* bp  = (const float*)d_in[5];
  const float* bng = (const float*)d_in[6];
  const float* bnb = (const float*)d_in[7];
  const float* bnm = (const float*)d_in[8];
  const float* bnv = (const float*)d_in[9];
  float* out = (float*)d_out;

  char* ws = (char*)d_ws;
  size_t off = 0;
  auto alloc = [&](size_t bytes) {
    char* p = ws + off;
    off += (bytes + 255) & ~(size_t)255;
    return p;
  };
  uint16_t* Xh   = (uint16_t*)alloc((size_t)8192 * 1024 * 2);       // 16MB
  uint16_t* XRh  = (uint16_t*)alloc((size_t)2048 * 1024 * 2);       // 4MB
  uint16_t* Wkvh = (uint16_t*)alloc((size_t)2048 * 1024 * 2);       // 4MB
  uint16_t* Wph  = (uint16_t*)alloc((size_t)1024 * 1024 * 2);       // 2MB
  uint16_t* KVcat= (uint16_t*)alloc((size_t)2 * 2048 * 2048 * 2);   // 16MB (2 bf16 halves)
  uint16_t* Gh   = (uint16_t*)alloc((size_t)4096 * 1024 * 2);       // 8MB
  unsigned* cnt  = (unsigned*)alloc(576 * 4);                       // barrier counters
  // overlays (lifetime-disjoint, phases separated by grid barriers):
  // KVcat dead after kv1 phase -> Tth (8MB = first half)
  uint16_t* Tth = KVcat;
  // kv partials (4MB) live only kv1 -> t phase, before GEMM5 writes Gh
  float* KVpart = (float*)Gh;

  // 1) fused prep: x split (hi) + XR pool/BN (hi) + weight splits (hi)
  //    + zero the 9 barrier counters
  prep_kernel<<<5120, 256, 0, stream>>>(x, bng, bnb, bnm, bnv, Wk, Wv, Wp,
                                        Xh, XRh, Wkvh, Wph, cnt);
  // 2) everything else in one persistent regular dispatch;
  //    all 512 blocks co-resident by construction
  MonoArgs ma;
  ma.XRh = XRh;   ma.Wkvh = Wkvh; ma.Xh = Xh;  ma.Wph = Wph;
  ma.KVcat = KVcat; ma.Tth = Tth; ma.Gh = Gh;  ma.KVpart = KVpart;
  ma.Wq = Wq;     ma.bp = bp;     ma.out = out; ma.cnt = cnt;
  mono_kernel<<<512, 256, 0, stream>>>(ma);
}

// Round 14
// 85.528 us; speedup vs baseline: 5.1714x; 1.2223x over previous
//
#include <hip/hip_runtime.h>
#include <stdint.h>

#define DEVFN __device__ __forceinline__

typedef __attribute__((ext_vector_type(8))) short s16x8;
typedef __attribute__((ext_vector_type(4))) float f32x4;

DEVFN float bf2f(uint16_t u) {
  union { uint32_t i; float f; } v; v.i = ((uint32_t)u) << 16; return v.f;
}
DEVFN uint16_t f2bf(float f) {
  union { float f; uint32_t i; } v; v.f = f;
  uint32_t u = v.i;
  return (uint16_t)((u + 0x7FFFu + ((u >> 16) & 1u)) >> 16);
}

DEVFN void gload_lds16(const void* g, void* l) {
  __builtin_amdgcn_global_load_lds(
      (const __attribute__((address_space(1))) uint32_t*)g,
      (__attribute__((address_space(3))) uint32_t*)l, 16, 0, 0);
}

// ---------------------------------------------------------------------------
// Fused prep: blocks 0..2047  : x -> Xh (hi) + XR = BN(AvgPool4) hi ONLY
//             blocks 2048..5119: Wk/Wv -> Wkvh (hi), Wp -> Wph (hi)
// ---------------------------------------------------------------------------
__global__ __launch_bounds__(256)
void prep_kernel(const float* __restrict__ x,
                 const float* __restrict__ bn_g, const float* __restrict__ bn_b,
                 const float* __restrict__ bn_m, const float* __restrict__ bn_v,
                 const float* __restrict__ Wk, const float* __restrict__ Wv,
                 const float* __restrict__ Wp,
                 uint16_t* __restrict__ Xh,
                 uint16_t* __restrict__ XRh,
                 uint16_t* __restrict__ Wkvh,
                 uint16_t* __restrict__ Wph)
{
  const int t = threadIdx.x;
  const int bid = blockIdx.x;
  if (bid < 2048) {
    const int prow = bid;                    // pooled row: b*512 + mm
    const int c0 = t * 4;
    const size_t xbase = (size_t)prow * 4096 + c0;   // x row prow*4
    float s[4] = {0.f, 0.f, 0.f, 0.f};
#pragma unroll
    for (int r = 0; r < 4; ++r) {
      const float4 w = *(const float4*)(x + xbase + (size_t)r * 1024);
      const float vv[4] = { w.x, w.y, w.z, w.w };
      uint64_t wh = 0;
#pragma unroll
      for (int j = 0; j < 4; ++j) {
        wh |= ((uint64_t)f2bf(vv[j])) << (16 * j);
        s[j] += vv[j];
      }
      *(uint64_t*)(Xh + xbase + (size_t)r * 1024) = wh;
    }
    uint64_t wh = 0;
#pragma unroll
    for (int j = 0; j < 4; ++j) {
      const int c = c0 + j;
      const float y = (s[j] * 0.25f - bn_m[c]) / sqrtf(bn_v[c] + 1e-6f) * bn_g[c] + bn_b[c];
      wh |= ((uint64_t)f2bf(y)) << (16 * j);
    }
    *(uint64_t*)(XRh + (size_t)prow * 1024 + c0) = wh;
  } else {
    const int wb = bid - 2048;               // 0..3071
    const int which = wb >> 10;
    const int i = (wb & 1023) * 256 + t;     // float4 index
    const float* src = (which == 0) ? Wk : (which == 1) ? Wv : Wp;
    const float4 v = ((const float4*)src)[i];
    const float vv[4] = { v.x, v.y, v.z, v.w };
    uint64_t wh = 0;
#pragma unroll
    for (int j = 0; j < 4; ++j)
      wh |= ((uint64_t)f2bf(vv[j])) << (16 * j);
    if (which == 2) {
      ((uint64_t*)Wph)[i] = wh;
    } else {
      ((uint64_t*)Wkvh)[(size_t)which * (1024 * 1024 / 4) + i] = wh;
    }
  }
}

// ---------------------------------------------------------------------------
// NT GEMM — r6 champion (measured 85.47): single LDS buffer, BK=128,
// 16x16x32 MFMA, register-frontload reorder. Per kt: sync -> ds_read ALL
// fragments -> sync -> STAGE(kt+1) into same buffer -> MFMA on registers.
// Session verdicts baked in: BK=128 amortization is the one real win (r2);
// 32x32 shape, dbuf/vmcnt pipelining, BM=64-everywhere, KV fusion, and the
// persistent mono-kernel (r10-13: capture-reject / fence-storm / spill)
// all null or negative. This structure is the keeper.
// C[m,n] = sum_k A[m,k]*B[n,k].
//   SMALLM=false: BM=128, waves 2x2, acc[4][4], LDS 64KB -> 2 blocks/CU.
//   SMALLM=true : BM=64,  waves 1x4, acc[4][2], LDS 48KB.
// LDS row = 256B (16 x 16B slots); phys slot s at row r holds src slot
// s ^ (r&7); ds_read same involution -> conflict-free (r2 measured).
// EPI: 0 = fp32 C32, 1 = bf16 hi Cb0, 2 = fp32 C32 + bias
// BATCHB: B advances N*K per rows_per_batch rows of A. AMODA: A row &1023.
// KSPLIT2: blockIdx.y in {0,1} selects K-half; C32/Cb0 += y*M*N.
// ---------------------------------------------------------------------------
template<bool BATCHB, bool AMODA, int EPI, bool KSPLIT2, bool SMALLM>
__global__ __launch_bounds__(256, 2)
void gemm_nt(const uint16_t* __restrict__ A0,
             const uint16_t* __restrict__ B0,
             float* __restrict__ C32, uint16_t* __restrict__ Cb0,
             const float* __restrict__ bias,
             int M, int N, int K, int rows_per_batch)
{
  constexpr int BM = SMALLM ? 64 : 128, BN = 128, BK = 128;
  constexpr int WCN = SMALLM ? 4 : 2;         // waves along N
  constexpr int WNW = BN / WCN;               // per-wave N width (32 or 64)
  constexpr int NREP = WNW / 16;              // 2 or 4
  constexpr int APASS = SMALLM ? 4 : 8;       // A staging passes (4KB each)
  constexpr int BPASS = 8;                    // B staging passes
  __shared__ uint16_t sA[BM * BK];
  __shared__ uint16_t sB[BN * BK];

  const int t = threadIdx.x;
  const int lane = t & 63;
  const int wave = t >> 6;
  const int wr = wave / WCN, wc = wave % WCN;
  const int fq = lane >> 4, fr = lane & 15;

  // T1: XCD-chunked swizzle (gridDim.x divisible by 8 for all our grids)
  const int nwg = gridDim.x;
  const int cpx = nwg >> 3;
  const int orig = blockIdx.x;
  const int swz = (orig & 7) * cpx + (orig >> 3);
  const int nbx = N >> 7;
  const int bm = (swz / nbx) * BM;
  const int bn = (swz % nbx) * BN;

  const uint16_t* Ap = A0;
  const uint16_t* Bp = B0;
  if (BATCHB)
    Bp += (size_t)(bm / rows_per_batch) * (size_t)N * (size_t)K;
  if (KSPLIT2) {
    const size_t half = (size_t)blockIdx.y * M * N;
    if (EPI == 1) Cb0 += half; else C32 += half;
  }

  f32x4 acc[4][NREP];
#pragma unroll
  for (int m = 0; m < 4; ++m)
#pragma unroll
    for (int n = 0; n < NREP; ++n) acc[m][n] = (f32x4)0.0f;

  auto STAGE = [&](int kt) {
#pragma unroll
    for (int i = 0; i < APASS; ++i) {
      const int X = t * 16 + i * 4096;          // linear LDS byte dest
      const int r = X >> 8;                     // row (256B per row)
      const int g = ((X >> 4) & 15) ^ (r & 7);  // pre-swizzled source slot
      const int kcol = (kt << 7) + g * 8;
      const int arow = AMODA ? ((bm + r) & 1023) : (bm + r);
      gload_lds16(Ap + (size_t)arow * K + kcol, (char*)(&sA[0]) + X);
    }
#pragma unroll
    for (int i = 0; i < BPASS; ++i) {
      const int X = t * 16 + i * 4096;
      const int r = X >> 8;
      const int g = ((X >> 4) & 15) ^ (r & 7);
      const int kcol = (kt << 7) + g * 8;
      gload_lds16(Bp + (size_t)(bn + r) * K + kcol, (char*)(&sB[0]) + X);
    }
  };

  const int nkt = K >> (KSPLIT2 ? 8 : 7);
  const int kt0 = KSPLIT2 ? (blockIdx.y * nkt) : 0;
  const int ktend = kt0 + nkt;

  STAGE(kt0);                                  // prologue prefetch
  for (int kt = kt0; kt < ktend; ++kt) {
    // drains this wave's staging loads (vmcnt 0) + barrier: tile kt ready.
    // Cover for those loads = previous iteration's MFMA phase.
    __syncthreads();

    // front-load the whole tile's fragments into registers
    s16x8 av[4][4], bv[4][NREP];               // [ks][.]
#pragma unroll
    for (int ks = 0; ks < 4; ++ks) {
#pragma unroll
      for (int m = 0; m < 4; ++m) {
        const int ra = wr * 64 + m * 16 + fr;
        const int offA = ra * 256 + ((((ks << 2) + fq) ^ (ra & 7)) << 4);
        av[ks][m] = *(const s16x8*)((const char*)(&sA[0]) + offA);
      }
#pragma unroll
      for (int n = 0; n < NREP; ++n) {
        const int rb = wc * WNW + n * 16 + fr;
        const int offB = rb * 256 + ((((ks << 2) + fq) ^ (rb & 7)) << 4);
        bv[ks][n] = *(const s16x8*)((const char*)(&sB[0]) + offB);
      }
    }

    // lgkm drained by syncthreads; after the barrier the LDS buffer is
    // dead (all waves hold their fragments) -> overwrite it early
    __syncthreads();
    if (kt + 1 < ktend) STAGE(kt + 1);

    // MFMA phase on registers (the latency cover for kt+1's loads)
#pragma unroll
    for (int ks = 0; ks < 4; ++ks)
#pragma unroll
      for (int m = 0; m < 4; ++m)
#pragma unroll
        for (int n = 0; n < NREP; ++n)
          acc[m][n] = __builtin_amdgcn_mfma_f32_16x16x32_bf16(
              av[ks][m], bv[ks][n], acc[m][n], 0, 0, 0);
  }

  // epilogue: C/D layout col = lane&15, row = (lane>>4)*4 + reg (m89/m91)
#pragma unroll
  for (int m = 0; m < 4; ++m) {
#pragma unroll
    for (int n = 0; n < NREP; ++n) {
#pragma unroll
      for (int j = 0; j < 4; ++j) {
        const int row = bm + wr * 64 + m * 16 + fq * 4 + j;
        const int col = bn + wc * WNW + n * 16 + fr;
        const size_t idx = (size_t)row * N + col;
        float v = acc[m][n][j];
        if constexpr (EPI == 0) {
          C32[idx] = v;
        } else if constexpr (EPI == 1) {
          Cb0[idx] = f2bf(v);
        } else {
          C32[idx] = v + bias[col];
        }
      }
    }
  }
}

// ---------------------------------------------------------------------------
// kv stage 1: partial[bid][f][e] = sum over 64 rows of K[.,f]*V[.,e].
// KVcat is bf16 in TWO split-K halves (stride 2048*2048); sum on stage (fp32).
// bid = bh*8 + ch. 1024 blocks -> full CU coverage.
// r14 fix (from r13 mono PMC: SQ_LDS_BANK_CONFLICT 4.8M): the old [64][32]
// scalar writes had bank = (q*8+j)&31 -> 16 lanes (same q) on one bank =
// 16-way conflict (5.69x, m136) on all 16 writes. Row stride 36 floats ->
// f32x4 writes land 8 lanes per 4-bank group (the b128 minimum) = conflict-
// free, and 16 scalar stores become 4 vector stores. Alignment: 36*4 = 144
// = 9*16 and e0*4 = 16*(t&7), both 16B-multiples. Reads: sK[mm][f] is a
// same-address broadcast per 8-lane group; sV f32x4 stays aligned.
// ---------------------------------------------------------------------------
__global__ __launch_bounds__(256)
void kv1_kernel(const uint16_t* __restrict__ KVcat, float* __restrict__ part)
{
  const int bid = blockIdx.x;
  const int bh = bid >> 3, ch = bid & 7;
  const int b = bh >> 5, h = bh & 31;
  const int t = threadIdx.x;
  __shared__ float sK[64][36];
  __shared__ float sV[64][36];
  const int f = t >> 3, e0 = (t & 7) * 4;
  const int lr = t >> 2, q = t & 3;
  const size_t rowb = (size_t)(b * 512 + ch * 64 + lr) * 2048 + h * 32 + q * 8;
  const size_t H = (size_t)2048 * 2048;   // second split-K half offset
  const s16x8 k0 = *(const s16x8*)(KVcat + rowb);
  const s16x8 k1 = *(const s16x8*)(KVcat + H + rowb);
  const s16x8 v0 = *(const s16x8*)(KVcat + rowb + 1024);
  const s16x8 v1 = *(const s16x8*)(KVcat + H + rowb + 1024);
  f32x4 kw0, kw1, vw0, vw1;
#pragma unroll
  for (int j = 0; j < 4; ++j) {
    kw0[j] = bf2f((uint16_t)k0[j])     + bf2f((uint16_t)k1[j]);
    kw1[j] = bf2f((uint16_t)k0[j + 4]) + bf2f((uint16_t)k1[j + 4]);
    vw0[j] = bf2f((uint16_t)v0[j])     + bf2f((uint16_t)v1[j]);
    vw1[j] = bf2f((uint16_t)v0[j + 4]) + bf2f((uint16_t)v1[j + 4]);
  }
  *(f32x4*)&sK[lr][q * 8]     = kw0;
  *(f32x4*)&sK[lr][q * 8 + 4] = kw1;
  *(f32x4*)&sV[lr][q * 8]     = vw0;
  *(f32x4*)&sV[lr][q * 8 + 4] = vw1;
  __syncthreads();
  float a0 = 0.f, a1 = 0.f, a2 = 0.f, a3 = 0.f;
#pragma unroll 16
  for (int mm = 0; mm < 64; ++mm) {
    const float kf = sK[mm][f];
    const float4 vv = *(const float4*)&sV[mm][e0];
    a0 += kf * vv.x; a1 += kf * vv.y; a2 += kf * vv.z; a3 += kf * vv.w;
  }
  float* o = part + ((size_t)bid * 32 + f) * 32 + e0;
  o[0] = a0; o[1] = a1; o[2] = a2; o[3] = a3;
}

// ---------------------------------------------------------------------------
// t_kernel (kv2 fused): KV[b,h] = scale * sum_ch part[bh*8+ch];
// Tt[b][c][h*32+e] = sum_f KV[b,h][f,e] * Wq[h*32+f, c]   (bf16 hi out)
// grid: 512 blocks = (b, h, c-chunk of 256); 256 threads = one c each.
// (sKV write pattern already distributes 8 lanes per 4-bank group = b128
// minimum; read side is uniform-address broadcast — no fix needed.)
// ---------------------------------------------------------------------------
__global__ __launch_bounds__(256)
void t_kernel(const float* __restrict__ part, const float* __restrict__ Wq,
              uint16_t* __restrict__ Tth)
{
  const int bid = blockIdx.x;        // b*128 + h*4 + cc
  const int b = bid >> 7, h = (bid >> 2) & 31, cc = bid & 3;
  const int bh = b * 32 + h;
  const int t = threadIdx.x;
  __shared__ float sKV[32][32];      // [f][e]
  {
    const int f = t >> 3, e0 = (t & 7) * 4;
    f32x4 a = (f32x4)0.0f;
#pragma unroll
    for (int ch = 0; ch < 8; ++ch)
      a += *(const f32x4*)(part + ((size_t)(bh * 8 + ch) * 32 + f) * 32 + e0);
    a *= 0.17677669529663687f;       // 1/sqrt(32)
    *(f32x4*)&sKV[f][e0] = a;
  }
  __syncthreads();
  const int c = cc * 256 + t;
  f32x4 acc[8];
#pragma unroll
  for (int i = 0; i < 8; ++i) acc[i] = (f32x4)0.0f;
  const float* wqp = Wq + (size_t)(h * 32) * 1024 + c;
#pragma unroll 8
  for (int f = 0; f < 32; ++f) {
    const float wq = wqp[(size_t)f * 1024];
#pragma unroll
    for (int i = 0; i < 8; ++i) {
      const f32x4 kv = *(const f32x4*)&sKV[f][i * 4];
      acc[i] += kv * wq;
    }
  }
  const size_t o = (((size_t)b << 10) + c) * 1024 + h * 32;
#pragma unroll
  for (int i = 0; i < 8; ++i) {
    uint64_t wh = 0;
#pragma unroll
    for (int j = 0; j < 4; ++j)
      wh |= ((uint64_t)f2bf(acc[i][j])) << (16 * j);
    *(uint64_t*)(Tth + o + i * 4) = wh;
  }
}

// ---------------------------------------------------------------------------
extern "C" void kernel_launch(void* const* d_in, const int* in_sizes, int n_in,
                              void* d_out, int out_size, void* d_ws, size_t ws_size,
                              hipStream_t stream)
{
  const float* x   = (const float*)d_in[0];
  const float* Wq  = (const float*)d_in[1];
  const float* Wk  = (const float*)d_in[2];
  const float* Wv  = (const float*)d_in[3];
  const float* Wp  = (const float*)d_in[4];
  const float* bp  = (const float*)d_in[5];
  const float* bng = (const float*)d_in[6];
  const float* bnb = (const float*)d_in[7];
  const float* bnm = (const float*)d_in[8];
  const float* bnv = (const float*)d_in[9];
  float* out = (float*)d_out;

  char* ws = (char*)d_ws;
  size_t off = 0;
  auto alloc = [&](size_t bytes) {
    char* p = ws + off;
    off += (bytes + 255) & ~(size_t)255;
    return p;
  };
  uint16_t* Xh   = (uint16_t*)alloc((size_t)8192 * 1024 * 2);       // 16MB
  uint16_t* XRh  = (uint16_t*)alloc((size_t)2048 * 1024 * 2);       // 4MB
  uint16_t* Wkvh = (uint16_t*)alloc((size_t)2048 * 1024 * 2);       // 4MB
  uint16_t* Wph  = (uint16_t*)alloc((size_t)1024 * 1024 * 2);       // 2MB
  uint16_t* KVcat= (uint16_t*)alloc((size_t)2 * 2048 * 2048 * 2);   // 16MB (2 bf16 halves)
  uint16_t* Gh   = (uint16_t*)alloc((size_t)4096 * 1024 * 2);       // 8MB
  // overlays (lifetime-disjoint):
  // KVcat dead after kv1 -> Tth (8MB = first half)
  uint16_t* Tth = KVcat;
  // kv partials (4MB) live only kv1 -> t_kernel, before G-GEMM writes Gh
  float* KVpart = (float*)Gh;

  // 1) fused prep: x split (hi) + XR pool/BN (hi) + weight splits (hi)
  prep_kernel<<<5120, 256, 0, stream>>>(x, bng, bnb, bnm, bnv, Wk, Wv, Wp,
                                        Xh, XRh, Wkvh, Wph);
  // 2) [K|V] = XRh @ [Wk;Wv]h^T (hh only), split-K x2, bf16 partial halves
  gemm_nt<false, false, 1, true, false><<<dim3(256, 2), 256, 0, stream>>>(
      XRh, Wkvh, nullptr, KVcat, nullptr,
      2048, 2048, 1024, 1 << 30);
  // 3) KV partials (sums the two bf16 split-K halves while staging)
  kv1_kernel<<<1024, 256, 0, stream>>>(KVcat, KVpart);
  // 4) Tt = (blockdiag(KV)^T Wq)^T, bf16 hi (kv2 fused; overlays KVcat)
  t_kernel<<<512, 256, 0, stream>>>(KVpart, Wq, Tth);
  // 5) G[b] = Wph @ Tt[b]^T (hh only), bf16 out, BM=64 -> 512 blocks (2/CU)
  gemm_nt<true, true, 1, false, true><<<512, 256, 0, stream>>>(
      Wph, Tth, nullptr, Gh, nullptr,
      4096, 1024, 1024, 1024);
  // 6) out = Xh @ G[b]^T + bp (hh only), fp32 out
  gemm_nt<true, false, 2, false, false><<<512, 256, 0, stream>>>(
      Xh, Gh, out, nullptr, bp,
      8192, 1024, 1024, 2048);
}